// Round 9
// baseline (274.098 us; speedup 1.0000x reference)
//
#include <hip/hip_runtime.h>
#include <hip/hip_bf16.h>

#define B_    32
#define L_    4096
#define H_    32
#define HKV_  2
#define GQ_   16
#define D_    128
#define HID_  4096
#define FFN_  13696
#define NQKV_ 4608
#define ROT_  64
#define EPS_  1e-5f

#define WAVE_POS_ 128
#define NSPLIT_   32   // L_ / WAVE_POS_

// KSPLIT per GEMM — chosen so grid <= 768 (= 3 blocks/CU co-residency cap at 48KB LDS)
#define KS_QKV_  16    // 36*16 = 576 blocks
#define KS_DEN_  24    // 32*24 = 768 blocks
#define KS_H4H_  3     // 214*3 = 642 blocks
#define KS_4HH_  24    // 32*24 = 768 blocks

typedef __attribute__((ext_vector_type(8))) __bf16 bf16x8;
typedef __attribute__((ext_vector_type(4))) float  f32x4;

__device__ __forceinline__ void gl_lds16(const float* g, float* l) {
    __builtin_amdgcn_global_load_lds((const __attribute__((address_space(1))) void*)g,
                                     (__attribute__((address_space(3))) void*)l, 16, 0, 0);
}

// ---------------------------------------------------------------- rmsnorm1 (1024 thr)
__global__ __launch_bounds__(1024) void rmsnorm1_k(const float* __restrict__ x,
                                                   const float* __restrict__ w,
                                                   __bf16* __restrict__ out)
{
    int b = blockIdx.x;
    const float* row = x + (size_t)b * HID_;
    float vals[4];
    float ss = 0.f;
#pragma unroll
    for (int i = 0; i < 4; ++i) {
        vals[i] = row[threadIdx.x + i * 1024];
        ss += vals[i] * vals[i];
    }
#pragma unroll
    for (int m = 1; m < 64; m <<= 1) ss += __shfl_xor(ss, m);
    __shared__ float wred[16];
    if ((threadIdx.x & 63) == 0) wred[threadIdx.x >> 6] = ss;
    __syncthreads();
    ss = 0.f;
#pragma unroll
    for (int wv = 0; wv < 16; ++wv) ss += wred[wv];
    float rs = rsqrtf(ss / HID_ + EPS_);
#pragma unroll
    for (int i = 0; i < 4; ++i) {
        int idx = threadIdx.x + i * 1024;
        out[(size_t)b * HID_ + idx] = (__bf16)(w[idx] * vals[i] * rs);
    }
}

// ---------------------------------------------------------------- skinny GEMM (R5-identical)
// A: [32][K] bf16 row-major.  W: [K][N] f32.  Cp: [KSPLIT][32][N] f32 partials.
template<int K, int N, int KSPLIT>
__global__ __launch_bounds__(256) void gemm16(const __bf16* __restrict__ A,
                                              const float* __restrict__ W,
                                              float* __restrict__ Cp)
{
    static_assert(K % 32 == 0, "K");
    constexpr int ksteps = K / 32;
    const int lane = threadIdx.x & 63;
    const int wid  = threadIdx.x >> 6;
    const int n0   = blockIdx.x * 128;
    const int cw   = wid * 32;
    const int r    = lane & 15;
    const int g4   = lane >> 4;
    const int s0   = (ksteps * (int)blockIdx.y) / KSPLIT;
    const int s1   = (ksteps * (int)(blockIdx.y + 1)) / KSPLIT;

    __shared__ float tiles[3][32][128];   // 48 KB

    const int rhalf = lane >> 5;          // 0/1 row within instruction
    const int mslot = lane & 31;          // 16B slot within row
    auto stage = [&](int s, float* dst) {
        if (s >= s1) return;
#pragma unroll
        for (int it = 0; it < 4; ++it) {
            int row  = wid * 8 + it * 2 + rhalf;
            int gcol = ((((mslot >> 1) ^ (row >> 3)) << 3) | ((mslot & 1) << 2));
            const float* src = W + (size_t)(s * 32 + row) * N + n0 + gcol;
            gl_lds16(src, dst + (size_t)(wid * 8 + it * 2) * 128);
        }
    };

    f32x4 acc00 = {0.f,0.f,0.f,0.f}, acc01 = acc00, acc10 = acc00, acc11 = acc00;
    const __bf16* a0p = A + (size_t)r * K;
    const __bf16* a1p = A + (size_t)(r + 16) * K;

    stage(s0,     &tiles[0][0][0]);
    stage(s0 + 1, &tiles[1][0][0]);

    const int c0 = cw + r, c1 = cw + r + 16;
    const int i0 = (((c0 >> 3) ^ g4) << 3) | (c0 & 7);
    const int i1 = (((c1 >> 3) ^ g4) << 3) | (c1 & 7);

    int bufc = 0;
    for (int s = s0; s < s1; ++s) {
        if (s + 1 < s1) asm volatile("s_waitcnt vmcnt(4)" ::: "memory");
        else            asm volatile("s_waitcnt vmcnt(0)" ::: "memory");
        __builtin_amdgcn_s_barrier();
        __builtin_amdgcn_sched_barrier(0);
        int bs = bufc + 2; if (bs >= 3) bs -= 3;
        stage(s + 2, &tiles[bs][0][0]);

        bf16x8 av0 = *(const bf16x8*)(a0p + s * 32 + g4 * 8);
        bf16x8 av1 = *(const bf16x8*)(a1p + s * 32 + g4 * 8);
        const float (*tile)[128] = tiles[bufc];
        bf16x8 b0f, b1f;
#pragma unroll
        for (int j = 0; j < 8; ++j) {
            b0f[j] = (__bf16)tile[g4 * 8 + j][i0];
            b1f[j] = (__bf16)tile[g4 * 8 + j][i1];
        }
        acc00 = __builtin_amdgcn_mfma_f32_16x16x32_bf16(av0, b0f, acc00, 0, 0, 0);
        acc10 = __builtin_amdgcn_mfma_f32_16x16x32_bf16(av1, b0f, acc10, 0, 0, 0);
        acc01 = __builtin_amdgcn_mfma_f32_16x16x32_bf16(av0, b1f, acc01, 0, 0, 0);
        acc11 = __builtin_amdgcn_mfma_f32_16x16x32_bf16(av1, b1f, acc11, 0, 0, 0);
        bufc = (bufc + 1 < 3) ? bufc + 1 : 0;
    }

    float* cp = Cp + ((size_t)blockIdx.y * 32) * N + n0 + cw;
#pragma unroll
    for (int i = 0; i < 4; ++i) {
        cp[(size_t)(g4 * 4 + i) * N + r]           = acc00[i];
        cp[(size_t)(g4 * 4 + i) * N + r + 16]      = acc01[i];
        cp[(size_t)(16 + g4 * 4 + i) * N + r]      = acc10[i];
        cp[(size_t)(16 + g4 * 4 + i) * N + r + 16] = acc11[i];
    }
}

// ---------------------------------------------------------------- qkv epilogue, wide: grid (B_,4)
__global__ __launch_bounds__(1024) void qkv_epi_k(const float* __restrict__ part, // [KS_QKV_][32][NQKV_]
                                                  const float* __restrict__ bias,
                                                  const int* __restrict__ ctxl,
                                                  __bf16* __restrict__ qbf,
                                                  float* __restrict__ knew,
                                                  float* __restrict__ vnew)
{
    __shared__ float rowv[1152];
    __shared__ float cs[32], sn[32];
    int b = blockIdx.x, base = blockIdx.y * 1152;
    int pos = ctxl[b];
    if (threadIdx.x < 32) {
        int t = threadIdx.x;
        float inv = powf(10000.f, -(float)t * (1.0f / 32.0f));
        float f = (float)pos * inv;
        float sv, cv; sincosf(f, &sv, &cv);
        cs[t] = cv; sn[t] = sv;
    }
    for (int i0 = threadIdx.x; i0 < 1152; i0 += 1024) {
        int i = base + i0;
        float v = bias[i];
#pragma unroll
        for (int p = 0; p < KS_QKV_; ++p) v += part[((size_t)p * B_ + b) * NQKV_ + i];
        rowv[i0] = v;
    }
    __syncthreads();
    const float qscale = 0.08838834764831845f; // 1/sqrt(128)
    for (int i0 = threadIdx.x; i0 < 1152; i0 += 1024) {
        int i = base + i0;
        int d = i & 127;
        if (i < HID_) {
            float o;
            if (d < ROT_) {
                int t = d >> 1;
                float cv = cs[t], sv = sn[t];
                float x1 = rowv[(i & ~1) - base], x2 = rowv[(i | 1) - base];
                o = (d & 1) ? (x2 * cv + x1 * sv) : (x1 * cv - x2 * sv);
            } else o = rowv[i0];
            qbf[(size_t)b * HID_ + i] = (__bf16)(o * qscale);
        } else {
            int j = i - HID_;            // 0..511
            if (j < HKV_ * D_) {         // k region
                float o;
                if (d < ROT_) {
                    int t = d >> 1;
                    float cv = cs[t], sv = sn[t];
                    float x1 = rowv[(i & ~1) - base], x2 = rowv[(i | 1) - base];
                    o = (d & 1) ? (x2 * cv + x1 * sv) : (x1 * cv - x2 * sv);
                } else o = rowv[i0];
                knew[(size_t)b * HKV_ * D_ + j] = o;
            } else {                     // v region
                vnew[(size_t)b * HKV_ * D_ + (j - HKV_ * D_)] = rowv[i0];
            }
        }
    }
}

// ---------------------------------------------------------------- flash-decode attention
// V tile (32x128) prefetched with 16 coalesced float4/lane at chunk top,
// staged to XOR-swizzled LDS after softmax; K preloaded for both pt.
// part: [B*HKV][NSPLIT_][16][130]  (128 acc, m, l) per head
__global__ __launch_bounds__(256) void attn_k(const float* __restrict__ kc,
                                              const float* __restrict__ vc,
                                              const float* __restrict__ knew,
                                              const float* __restrict__ vnew,
                                              const __bf16* __restrict__ qbf,
                                              const int* __restrict__ ctxl,
                                              float* __restrict__ part)
{
    const int bg  = blockIdx.x;            // 0..63
    const int b   = bg >> 1, g = bg & 1;
    const int wid = threadIdx.x >> 6;
    const int split = blockIdx.y * 4 + wid;  // 0..NSPLIT_-1
    const int ctx = ctxl[b];
    const int p0  = split * WAVE_POS_;
    __shared__ __bf16 plds_all[4][16][40];
    __shared__ __align__(16) float vlds_all[4][32][132];   // rows 16B-aligned
    if (p0 > ctx) return;
    const int pend = min(p0 + WAVE_POS_ - 1, ctx);
    const int lane = threadIdx.x & 63;
    const int r = lane & 15, g4 = lane >> 4;
    const int vrow2 = lane >> 5;           // 0/1: row within 2-row instruction
    const int vcol  = (lane & 31) * 4;     // float col 0..124

    bf16x8 qf[4];
    {
        const __bf16* qp = qbf + (size_t)b * HID_ + (g * GQ_ + r) * D_ + g4 * 8;
#pragma unroll
        for (int kk = 0; kk < 4; ++kk) qf[kk] = *(const bf16x8*)(qp + kk * 32);
    }
    f32x4 acc[8];
#pragma unroll
    for (int dt = 0; dt < 8; ++dt) acc[dt] = (f32x4){0.f,0.f,0.f,0.f};
    float m_run[4], l_run[4];
#pragma unroll
    for (int i = 0; i < 4; ++i) { m_run[i] = -1e30f; l_run[i] = 0.f; }

    auto plds = plds_all[wid];
    float (*vlds)[132] = vlds_all[wid];
    const float* kbase = kc + ((size_t)b * L_ * HKV_ + g) * D_;
    const float* vbase = vc + ((size_t)b * L_ * HKV_ + g) * D_;
    const float* knp = knew + (size_t)(b * HKV_ + g) * D_;
    const float* vnp = vnew + (size_t)(b * HKV_ + g) * D_;

    for (int pc = p0; pc <= pend; pc += 32) {
        // ---- issue full V tile early: 16 float4/lane, 2 rows per instruction
        float4 vreg[16];
#pragma unroll
        for (int t = 0; t < 16; ++t) {
            int row = t * 2 + vrow2;
            int pos = pc + row;
            const float* vr = (pos == ctx) ? vnp : vbase + (size_t)pos * (HKV_ * D_);
            vreg[t] = *(const float4*)(vr + vcol);
        }
        // ---- preload K for both pt sub-tiles
        bf16x8 kfr[2][4];
#pragma unroll
        for (int pt = 0; pt < 2; ++pt) {
            int pos = pc + pt * 16 + r;
            const float* krow = (pos == ctx) ? knp : kbase + (size_t)pos * (HKV_ * D_);
#pragma unroll
            for (int kk = 0; kk < 4; ++kk) {
                const float4* kp = (const float4*)(krow + kk * 32 + g4 * 8);
                float4 fa = kp[0], fb = kp[1];
                kfr[pt][kk] = (bf16x8){ (__bf16)fa.x, (__bf16)fa.y, (__bf16)fa.z, (__bf16)fa.w,
                                        (__bf16)fb.x, (__bf16)fb.y, (__bf16)fb.z, (__bf16)fb.w };
            }
        }
        // ---- QK^T
        f32x4 sf[2];
#pragma unroll
        for (int pt = 0; pt < 2; ++pt) {
            f32x4 s = {0.f,0.f,0.f,0.f};
#pragma unroll
            for (int kk = 0; kk < 4; ++kk)
                s = __builtin_amdgcn_mfma_f32_16x16x32_bf16(qf[kk], kfr[pt][kk], s, 0, 0, 0);
            sf[pt] = s;
        }
        // ---- mask
#pragma unroll
        for (int pt = 0; pt < 2; ++pt) {
            int pos = pc + pt * 16 + r;
            if (pos > ctx) {
#pragma unroll
                for (int i = 0; i < 4; ++i) sf[pt][i] = -1e30f;
            }
        }
        // ---- online softmax (per-head chunk max via 16-lane butterfly)
#pragma unroll
        for (int i = 0; i < 4; ++i) {
            float mv = fmaxf(sf[0][i], sf[1][i]);
            mv = fmaxf(mv, __shfl_xor(mv, 1));
            mv = fmaxf(mv, __shfl_xor(mv, 2));
            mv = fmaxf(mv, __shfl_xor(mv, 4));
            mv = fmaxf(mv, __shfl_xor(mv, 8));
            float mnew = fmaxf(m_run[i], mv);
            float sc = __expf(m_run[i] - mnew);
            l_run[i] *= sc;
            m_run[i] = mnew;
#pragma unroll
            for (int dt = 0; dt < 8; ++dt) acc[dt][i] *= sc;
        }
        // ---- exp, stage P into LDS in PV-A-fragment layout
#pragma unroll
        for (int pt = 0; pt < 2; ++pt) {
#pragma unroll
            for (int i = 0; i < 4; ++i) {
                float e = __expf(sf[pt][i] - m_run[i]);
                l_run[i] += e;
                plds[g4 * 4 + i][pt * 16 + r] = (__bf16)e;
            }
        }
        // ---- stage V to LDS (loads landed under QK+softmax); XOR bit-4 with row>>3&1
#pragma unroll
        for (int t = 0; t < 16; ++t) {
            int row = t * 2 + vrow2;
            int c2  = vcol ^ (((row >> 3) & 1) << 4);
            *(float4*)&vlds[row][c2] = vreg[t];
        }
        asm volatile("s_waitcnt lgkmcnt(0)" ::: "memory");
        __builtin_amdgcn_sched_barrier(0);
        bf16x8 pa = *(const bf16x8*)&plds[r][g4 * 8];
        // ---- PV from LDS (read applies same XOR; row>>3&1 == g4&1)
#pragma unroll
        for (int dt = 0; dt < 8; ++dt) {
            bf16x8 vf;
            int cread = (dt * 16 + r) ^ ((g4 & 1) << 4);
#pragma unroll
            for (int j = 0; j < 8; ++j) vf[j] = (__bf16)vlds[g4 * 8 + j][cread];
            acc[dt] = __builtin_amdgcn_mfma_f32_16x16x32_bf16(pa, vf, acc[dt], 0, 0, 0);
        }
        asm volatile("s_waitcnt lgkmcnt(0)" ::: "memory");
        __builtin_amdgcn_sched_barrier(0);
    }
    // ---- finalize l across the 16-lane group
#pragma unroll
    for (int i = 0; i < 4; ++i) {
        float lv = l_run[i];
        lv += __shfl_xor(lv, 1);
        lv += __shfl_xor(lv, 2);
        lv += __shfl_xor(lv, 4);
        lv += __shfl_xor(lv, 8);
        l_run[i] = lv;
    }
    float* pb = part + ((size_t)bg * NSPLIT_ + split) * 16 * 130;
#pragma unroll
    for (int dt = 0; dt < 8; ++dt)
#pragma unroll
        for (int i = 0; i < 4; ++i)
            pb[(g4 * 4 + i) * 130 + dt * 16 + r] = acc[dt][i];
    if (r == 0) {
#pragma unroll
        for (int i = 0; i < 4; ++i) {
            pb[(g4 * 4 + i) * 130 + 128] = m_run[i];
            pb[(g4 * 4 + i) * 130 + 129] = l_run[i];
        }
    }
}

// ---------------------------------------------------------------- attention combine (parallel)
// grid (B_*HKV_, 2), 1024 threads: block (bg,c) covers d in [c*64, c*64+64)
__global__ __launch_bounds__(1024) void attn_comb_k(const float* __restrict__ part,
                                                    const int* __restrict__ ctxl,
                                                    __bf16* __restrict__ ctxb)
{
    int bg = blockIdx.x;
    int c  = blockIdx.y;
    int b = bg >> 1, g = bg & 1;
    int ctx = ctxl[b];
    int ns = ctx / WAVE_POS_ + 1;
    const float* pb = part + (size_t)bg * NSPLIT_ * 16 * 130;
    __shared__ float mlm[NSPLIT_][16], wgt[NSPLIT_][16];
    __shared__ float Mh[16], Ih[16];
    int t = threadIdx.x;
    if (t < NSPLIT_ * 16) {
        int s = t >> 4, h = t & 15;
        mlm[s][h] = pb[(s * 16 + h) * 130 + 128];
        wgt[s][h] = pb[(s * 16 + h) * 130 + 129];
    }
    __syncthreads();
    if (t < 16) {
        int h = t;
        float M = -1e30f;
        for (int s = 0; s < ns; ++s) M = fmaxf(M, mlm[s][h]);
        float den = 0.f;
        for (int s = 0; s < ns; ++s) den += __expf(mlm[s][h] - M) * wgt[s][h];
        Mh[h] = M; Ih[h] = 1.f / den;
    }
    __syncthreads();
    if (t < NSPLIT_ * 16) {
        int s = t >> 4, h = t & 15;
        wgt[s][h] = __expf(mlm[s][h] - Mh[h]) * Ih[h];
    }
    __syncthreads();
    int h = t >> 6, dd = (t & 63) + c * 64;
    float o = 0.f;
    for (int s = 0; s < ns; ++s)
        o += wgt[s][h] * pb[(s * 16 + h) * 130 + dd];
    ctxb[(size_t)b * HID_ + (g * GQ_ + h) * D_ + dd] = (__bf16)o;
}

// ---------------------------------------------------------------- dense reduce (wide): grid (B_,4)
__global__ __launch_bounds__(1024) void dense_red_k(const float* __restrict__ hidden,
                                                    const float* __restrict__ partd, // [KS_DEN_][32][HID_]
                                                    float* __restrict__ xout,
                                                    float* __restrict__ ssq) // [B_][4]
{
    int b = blockIdx.x;
    int i = blockIdx.y * 1024 + threadIdx.x;
    float v = hidden[(size_t)b * HID_ + i];
#pragma unroll
    for (int p = 0; p < KS_DEN_; ++p) v += partd[((size_t)p * B_ + b) * HID_ + i];
    xout[(size_t)b * HID_ + i] = v;
    float ss = v * v;
#pragma unroll
    for (int m = 1; m < 64; m <<= 1) ss += __shfl_xor(ss, m);
    __shared__ float wred[16];
    if ((threadIdx.x & 63) == 0) wred[threadIdx.x >> 6] = ss;
    __syncthreads();
    if (threadIdx.x == 0) {
        float s = 0.f;
#pragma unroll
        for (int wv = 0; wv < 16; ++wv) s += wred[wv];
        ssq[b * 4 + blockIdx.y] = s;
    }
}

// ---------------------------------------------------------------- rmsnorm2 (narrow): grid B_
__global__ __launch_bounds__(1024) void rms2_k(const float* __restrict__ xbuf,
                                               const float* __restrict__ ssq,
                                               const float* __restrict__ wln2,
                                               __bf16* __restrict__ a2)
{
    int b = blockIdx.x;
    float ss = ssq[b * 4] + ssq[b * 4 + 1] + ssq[b * 4 + 2] + ssq[b * 4 + 3];
    float rs = rsqrtf(ss / HID_ + EPS_);
#pragma unroll
    for (int it = 0; it < 4; ++it) {
        int i = threadIdx.x + it * 1024;
        a2[(size_t)b * HID_ + i] = (__bf16)(wln2[i] * xbuf[(size_t)b * HID_ + i] * rs);
    }
}

// ---------------------------------------------------------------- swiglu activation (sums KS_H4H_ slabs)
__global__ __launch_bounds__(256) void act_k(const float* __restrict__ gu, // [KS_H4H_][32][2*FFN_]
                                             __bf16* __restrict__ act)
{
    int i = blockIdx.x * 256 + threadIdx.x;
    int b = blockIdx.y;
    if (i < FFN_) {
        float gv = 0.f, uv = 0.f;
#pragma unroll
        for (int p = 0; p < KS_H4H_; ++p) {
            const float* gp = gu + ((size_t)p * B_ + b) * 2 * FFN_;
            gv += gp[i];
            uv += gp[FFN_ + i];
        }
        float s = gv / (1.f + __expf(-gv));
        act[(size_t)b * FFN_ + i] = (__bf16)(s * uv);
    }
}

// ---------------------------------------------------------------- final residual
__global__ __launch_bounds__(256) void out_epi_k(const float* __restrict__ x,
                                                 const float* __restrict__ part4, // [KS_4HH_][32][HID_]
                                                 float* __restrict__ out)
{
    int i = blockIdx.x * 256 + threadIdx.x;
    float v = x[i];
#pragma unroll
    for (int p = 0; p < KS_4HH_; ++p) v += part4[(size_t)p * (B_ * HID_) + i];
    out[i] = v;
}

// ---------------------------------------------------------------- launch
extern "C" void kernel_launch(void* const* d_in, const int* in_sizes, int n_in,
                              void* d_out, int out_size, void* d_ws, size_t ws_size,
                              hipStream_t stream)
{
    const float* hidden  = (const float*)d_in[0];
    const int*   ctxl    = (const int*)d_in[1];
    const float* kcache  = (const float*)d_in[2];
    const float* vcache  = (const float*)d_in[3];
    const float* w_ln1   = (const float*)d_in[4];
    const float* w_ln2   = (const float*)d_in[5];
    const float* w_qkv   = (const float*)d_in[6];
    const float* b_qkv   = (const float*)d_in[7];
    const float* w_dense = (const float*)d_in[8];
    const float* w_h4h   = (const float*)d_in[9];
    const float* w_4hh   = (const float*)d_in[10];
    float* out = (float*)d_out;

    char* ws = (char*)d_ws;
    size_t off = 0;
    auto alloc = [&](size_t bytes) -> void* {
        void* p = ws + off;
        off += (bytes + 255) & ~(size_t)255;
        return p;
    };
    __bf16* a0    = (__bf16*)alloc((size_t)B_ * HID_ * 2);
    float*  partq = (float*) alloc((size_t)KS_QKV_ * B_ * NQKV_ * 4);
    __bf16* qbf   = (__bf16*)alloc((size_t)B_ * HID_ * 2);
    float*  knew  = (float*) alloc((size_t)B_ * HKV_ * D_ * 4);
    float*  vnew  = (float*) alloc((size_t)B_ * HKV_ * D_ * 4);
    float*  apart = (float*) alloc((size_t)B_ * HKV_ * NSPLIT_ * 16 * 130 * 4);
    __bf16* ctxb  = (__bf16*)alloc((size_t)B_ * HID_ * 2);
    float*  partd = (float*) alloc((size_t)KS_DEN_ * B_ * HID_ * 4);
    float*  xbuf  = (float*) alloc((size_t)B_ * HID_ * 4);
    float*  ssq   = (float*) alloc((size_t)B_ * 4 * 4);
    __bf16* a2    = (__bf16*)alloc((size_t)B_ * HID_ * 2);
    float*  gu    = (float*) alloc((size_t)KS_H4H_ * B_ * 2 * FFN_ * 4);
    __bf16* actb  = (__bf16*)alloc((size_t)B_ * FFN_ * 2);
    float*  part4 = (float*) alloc((size_t)KS_4HH_ * B_ * HID_ * 4);
    (void)ws_size; (void)in_sizes; (void)n_in; (void)out_size;

    hipLaunchKernelGGL(rmsnorm1_k, dim3(B_), dim3(1024), 0, stream, hidden, w_ln1, a0);
    hipLaunchKernelGGL((gemm16<HID_, NQKV_, KS_QKV_>), dim3(NQKV_ / 128, KS_QKV_), dim3(256), 0, stream, a0, w_qkv, partq);
    hipLaunchKernelGGL(qkv_epi_k, dim3(B_, 4), dim3(1024), 0, stream, partq, b_qkv, ctxl, qbf, knew, vnew);
    hipLaunchKernelGGL(attn_k, dim3(B_ * HKV_, NSPLIT_ / 4), dim3(256), 0, stream,
                       kcache, vcache, knew, vnew, qbf, ctxl, apart);
    hipLaunchKernelGGL(attn_comb_k, dim3(B_ * HKV_, 2), dim3(1024), 0, stream, apart, ctxl, ctxb);
    hipLaunchKernelGGL((gemm16<HID_, HID_, KS_DEN_>), dim3(HID_ / 128, KS_DEN_), dim3(256), 0, stream, ctxb, w_dense, partd);
    hipLaunchKernelGGL(dense_red_k, dim3(B_, 4), dim3(1024), 0, stream, hidden, partd, xbuf, ssq);
    hipLaunchKernelGGL(rms2_k, dim3(B_), dim3(1024), 0, stream, xbuf, ssq, w_ln2, a2);
    hipLaunchKernelGGL((gemm16<HID_, 2 * FFN_, KS_H4H_>), dim3(2 * FFN_ / 128, KS_H4H_), dim3(256), 0, stream, a2, w_h4h, gu);
    hipLaunchKernelGGL(act_k, dim3((FFN_ + 255) / 256, B_), dim3(256), 0, stream, gu, actb);
    hipLaunchKernelGGL((gemm16<FFN_, HID_, KS_4HH_>), dim3(HID_ / 128, KS_4HH_), dim3(256), 0, stream, actb, w_4hh, part4);
    hipLaunchKernelGGL(out_epi_k, dim3(B_ * HID_ / 256), dim3(256), 0, stream, xbuf, part4, out);
}

// Round 10
// 265.344 us; speedup vs baseline: 1.0330x; 1.0330x over previous
//
#include <hip/hip_runtime.h>
#include <hip/hip_bf16.h>

#define B_    32
#define L_    4096
#define H_    32
#define HKV_  2
#define GQ_   16
#define D_    128
#define HID_  4096
#define FFN_  13696
#define NQKV_ 4608
#define ROT_  64
#define EPS_  1e-5f

#define WAVE_POS_ 128
#define NSPLIT_   32   // L_ / WAVE_POS_

// KSPLIT per GEMM — chosen so grid <= 768 (= 3 blocks/CU co-residency cap at 48KB LDS)
#define KS_QKV_  16    // 36*16 = 576 blocks
#define KS_DEN_  24    // 32*24 = 768 blocks
#define KS_H4H_  3     // 214*3 = 642 blocks
#define KS_4HH_  24    // 32*24 = 768 blocks

typedef __attribute__((ext_vector_type(8))) __bf16 bf16x8;
typedef __attribute__((ext_vector_type(4))) float  f32x4;

__device__ __forceinline__ void gl_lds16(const float* g, float* l) {
    __builtin_amdgcn_global_load_lds((const __attribute__((address_space(1))) void*)g,
                                     (__attribute__((address_space(3))) void*)l, 16, 0, 0);
}

// ---------------------------------------------------------------- rmsnorm1 (1024 thr)
__global__ __launch_bounds__(1024) void rmsnorm1_k(const float* __restrict__ x,
                                                   const float* __restrict__ w,
                                                   __bf16* __restrict__ out)
{
    int b = blockIdx.x;
    const float* row = x + (size_t)b * HID_;
    float vals[4];
    float ss = 0.f;
#pragma unroll
    for (int i = 0; i < 4; ++i) {
        vals[i] = row[threadIdx.x + i * 1024];
        ss += vals[i] * vals[i];
    }
#pragma unroll
    for (int m = 1; m < 64; m <<= 1) ss += __shfl_xor(ss, m);
    __shared__ float wred[16];
    if ((threadIdx.x & 63) == 0) wred[threadIdx.x >> 6] = ss;
    __syncthreads();
    ss = 0.f;
#pragma unroll
    for (int wv = 0; wv < 16; ++wv) ss += wred[wv];
    float rs = rsqrtf(ss / HID_ + EPS_);
#pragma unroll
    for (int i = 0; i < 4; ++i) {
        int idx = threadIdx.x + i * 1024;
        out[(size_t)b * HID_ + idx] = (__bf16)(w[idx] * vals[i] * rs);
    }
}

// ---------------------------------------------------------------- skinny GEMM (R5-identical)
// A: [32][K] bf16 row-major.  W: [K][N] f32.  Cp: [KSPLIT][32][N] f32 partials.
template<int K, int N, int KSPLIT>
__global__ __launch_bounds__(256) void gemm16(const __bf16* __restrict__ A,
                                              const float* __restrict__ W,
                                              float* __restrict__ Cp)
{
    static_assert(K % 32 == 0, "K");
    constexpr int ksteps = K / 32;
    const int lane = threadIdx.x & 63;
    const int wid  = threadIdx.x >> 6;
    const int n0   = blockIdx.x * 128;
    const int cw   = wid * 32;
    const int r    = lane & 15;
    const int g4   = lane >> 4;
    const int s0   = (ksteps * (int)blockIdx.y) / KSPLIT;
    const int s1   = (ksteps * (int)(blockIdx.y + 1)) / KSPLIT;

    __shared__ float tiles[3][32][128];   // 48 KB

    const int rhalf = lane >> 5;          // 0/1 row within instruction
    const int mslot = lane & 31;          // 16B slot within row
    auto stage = [&](int s, float* dst) {
        if (s >= s1) return;
#pragma unroll
        for (int it = 0; it < 4; ++it) {
            int row  = wid * 8 + it * 2 + rhalf;
            int gcol = ((((mslot >> 1) ^ (row >> 3)) << 3) | ((mslot & 1) << 2));
            const float* src = W + (size_t)(s * 32 + row) * N + n0 + gcol;
            gl_lds16(src, dst + (size_t)(wid * 8 + it * 2) * 128);
        }
    };

    f32x4 acc00 = {0.f,0.f,0.f,0.f}, acc01 = acc00, acc10 = acc00, acc11 = acc00;
    const __bf16* a0p = A + (size_t)r * K;
    const __bf16* a1p = A + (size_t)(r + 16) * K;

    stage(s0,     &tiles[0][0][0]);
    stage(s0 + 1, &tiles[1][0][0]);

    const int c0 = cw + r, c1 = cw + r + 16;
    const int i0 = (((c0 >> 3) ^ g4) << 3) | (c0 & 7);
    const int i1 = (((c1 >> 3) ^ g4) << 3) | (c1 & 7);

    int bufc = 0;
    for (int s = s0; s < s1; ++s) {
        if (s + 1 < s1) asm volatile("s_waitcnt vmcnt(4)" ::: "memory");
        else            asm volatile("s_waitcnt vmcnt(0)" ::: "memory");
        __builtin_amdgcn_s_barrier();
        __builtin_amdgcn_sched_barrier(0);
        int bs = bufc + 2; if (bs >= 3) bs -= 3;
        stage(s + 2, &tiles[bs][0][0]);

        bf16x8 av0 = *(const bf16x8*)(a0p + s * 32 + g4 * 8);
        bf16x8 av1 = *(const bf16x8*)(a1p + s * 32 + g4 * 8);
        const float (*tile)[128] = tiles[bufc];
        bf16x8 b0f, b1f;
#pragma unroll
        for (int j = 0; j < 8; ++j) {
            b0f[j] = (__bf16)tile[g4 * 8 + j][i0];
            b1f[j] = (__bf16)tile[g4 * 8 + j][i1];
        }
        acc00 = __builtin_amdgcn_mfma_f32_16x16x32_bf16(av0, b0f, acc00, 0, 0, 0);
        acc10 = __builtin_amdgcn_mfma_f32_16x16x32_bf16(av1, b0f, acc10, 0, 0, 0);
        acc01 = __builtin_amdgcn_mfma_f32_16x16x32_bf16(av0, b1f, acc01, 0, 0, 0);
        acc11 = __builtin_amdgcn_mfma_f32_16x16x32_bf16(av1, b1f, acc11, 0, 0, 0);
        bufc = (bufc + 1 < 3) ? bufc + 1 : 0;
    }

    float* cp = Cp + ((size_t)blockIdx.y * 32) * N + n0 + cw;
#pragma unroll
    for (int i = 0; i < 4; ++i) {
        cp[(size_t)(g4 * 4 + i) * N + r]           = acc00[i];
        cp[(size_t)(g4 * 4 + i) * N + r + 16]      = acc01[i];
        cp[(size_t)(16 + g4 * 4 + i) * N + r]      = acc10[i];
        cp[(size_t)(16 + g4 * 4 + i) * N + r + 16] = acc11[i];
    }
}

// ---------------------------------------------------------------- qkv epilogue, wide: grid (B_,4)
__global__ __launch_bounds__(1024) void qkv_epi_k(const float* __restrict__ part, // [KS_QKV_][32][NQKV_]
                                                  const float* __restrict__ bias,
                                                  const int* __restrict__ ctxl,
                                                  __bf16* __restrict__ qbf,
                                                  float* __restrict__ knew,
                                                  float* __restrict__ vnew)
{
    __shared__ float rowv[1152];
    __shared__ float cs[32], sn[32];
    int b = blockIdx.x, base = blockIdx.y * 1152;
    int pos = ctxl[b];
    if (threadIdx.x < 32) {
        int t = threadIdx.x;
        float inv = powf(10000.f, -(float)t * (1.0f / 32.0f));
        float f = (float)pos * inv;
        float sv, cv; sincosf(f, &sv, &cv);
        cs[t] = cv; sn[t] = sv;
    }
    for (int i0 = threadIdx.x; i0 < 1152; i0 += 1024) {
        int i = base + i0;
        float v = bias[i];
#pragma unroll
        for (int p = 0; p < KS_QKV_; ++p) v += part[((size_t)p * B_ + b) * NQKV_ + i];
        rowv[i0] = v;
    }
    __syncthreads();
    const float qscale = 0.08838834764831845f; // 1/sqrt(128)
    for (int i0 = threadIdx.x; i0 < 1152; i0 += 1024) {
        int i = base + i0;
        int d = i & 127;
        if (i < HID_) {
            float o;
            if (d < ROT_) {
                int t = d >> 1;
                float cv = cs[t], sv = sn[t];
                float x1 = rowv[(i & ~1) - base], x2 = rowv[(i | 1) - base];
                o = (d & 1) ? (x2 * cv + x1 * sv) : (x1 * cv - x2 * sv);
            } else o = rowv[i0];
            qbf[(size_t)b * HID_ + i] = (__bf16)(o * qscale);
        } else {
            int j = i - HID_;            // 0..511
            if (j < HKV_ * D_) {         // k region
                float o;
                if (d < ROT_) {
                    int t = d >> 1;
                    float cv = cs[t], sv = sn[t];
                    float x1 = rowv[(i & ~1) - base], x2 = rowv[(i | 1) - base];
                    o = (d & 1) ? (x2 * cv + x1 * sv) : (x1 * cv - x2 * sv);
                } else o = rowv[i0];
                knew[(size_t)b * HKV_ * D_ + j] = o;
            } else {                     // v region
                vnew[(size_t)b * HKV_ * D_ + (j - HKV_ * D_)] = rowv[i0];
            }
        }
    }
}

// ---------------------------------------------------------------- flash-decode attention
// K loads issued FIRST, V tile second -> QK^T waits vmcnt(16) (K only), V's
// HBM latency hides under QK+softmax; V staged to XOR-swizzled LDS for PV.
// part: [B*HKV][NSPLIT_][16][130]  (128 acc, m, l) per head
__global__ __launch_bounds__(256) void attn_k(const float* __restrict__ kc,
                                              const float* __restrict__ vc,
                                              const float* __restrict__ knew,
                                              const float* __restrict__ vnew,
                                              const __bf16* __restrict__ qbf,
                                              const int* __restrict__ ctxl,
                                              float* __restrict__ part)
{
    const int bg  = blockIdx.x;            // 0..63
    const int b   = bg >> 1, g = bg & 1;
    const int wid = threadIdx.x >> 6;
    const int split = blockIdx.y * 4 + wid;  // 0..NSPLIT_-1
    const int ctx = ctxl[b];
    const int p0  = split * WAVE_POS_;
    __shared__ __bf16 plds_all[4][16][40];
    __shared__ __align__(16) float vlds_all[4][32][132];   // rows 16B-aligned
    if (p0 > ctx) return;
    const int pend = min(p0 + WAVE_POS_ - 1, ctx);
    const int lane = threadIdx.x & 63;
    const int r = lane & 15, g4 = lane >> 4;
    const int vrow2 = lane >> 5;           // 0/1: row within 2-row instruction
    const int vcol  = (lane & 31) * 4;     // float col 0..124

    bf16x8 qf[4];
    {
        const __bf16* qp = qbf + (size_t)b * HID_ + (g * GQ_ + r) * D_ + g4 * 8;
#pragma unroll
        for (int kk = 0; kk < 4; ++kk) qf[kk] = *(const bf16x8*)(qp + kk * 32);
    }
    f32x4 acc[8];
#pragma unroll
    for (int dt = 0; dt < 8; ++dt) acc[dt] = (f32x4){0.f,0.f,0.f,0.f};
    float m_run[4], l_run[4];
#pragma unroll
    for (int i = 0; i < 4; ++i) { m_run[i] = -1e30f; l_run[i] = 0.f; }

    auto plds = plds_all[wid];
    float (*vlds)[132] = vlds_all[wid];
    const float* kbase = kc + ((size_t)b * L_ * HKV_ + g) * D_;
    const float* vbase = vc + ((size_t)b * L_ * HKV_ + g) * D_;
    const float* knp = knew + (size_t)(b * HKV_ + g) * D_;
    const float* vnp = vnew + (size_t)(b * HKV_ + g) * D_;

    for (int pc = p0; pc <= pend; pc += 32) {
        // ---- issue K loads FIRST (raw float4; consumed right after)
        float4 kraw[2][4][2];
#pragma unroll
        for (int pt = 0; pt < 2; ++pt) {
            int pos = pc + pt * 16 + r;
            const float* krow = (pos == ctx) ? knp : kbase + (size_t)pos * (HKV_ * D_);
#pragma unroll
            for (int kk = 0; kk < 4; ++kk) {
                const float4* kp = (const float4*)(krow + kk * 32 + g4 * 8);
                kraw[pt][kk][0] = kp[0];
                kraw[pt][kk][1] = kp[1];
            }
        }
        // ---- then issue full V tile (newest outstanding -> K-wait leaves V in flight)
        float4 vreg[16];
#pragma unroll
        for (int t = 0; t < 16; ++t) {
            int row = t * 2 + vrow2;
            int pos = pc + row;
            const float* vr = (pos == ctx) ? vnp : vbase + (size_t)pos * (HKV_ * D_);
            vreg[t] = *(const float4*)(vr + vcol);
        }
        // ---- QK^T (compiler waits only on K: counted vmcnt)
        f32x4 sf[2];
#pragma unroll
        for (int pt = 0; pt < 2; ++pt) {
            f32x4 s = {0.f,0.f,0.f,0.f};
#pragma unroll
            for (int kk = 0; kk < 4; ++kk) {
                float4 fa = kraw[pt][kk][0], fb = kraw[pt][kk][1];
                bf16x8 kf = { (__bf16)fa.x, (__bf16)fa.y, (__bf16)fa.z, (__bf16)fa.w,
                              (__bf16)fb.x, (__bf16)fb.y, (__bf16)fb.z, (__bf16)fb.w };
                s = __builtin_amdgcn_mfma_f32_16x16x32_bf16(qf[kk], kf, s, 0, 0, 0);
            }
            sf[pt] = s;
        }
        // ---- mask
#pragma unroll
        for (int pt = 0; pt < 2; ++pt) {
            int pos = pc + pt * 16 + r;
            if (pos > ctx) {
#pragma unroll
                for (int i = 0; i < 4; ++i) sf[pt][i] = -1e30f;
            }
        }
        // ---- online softmax (per-head chunk max via 16-lane butterfly)
#pragma unroll
        for (int i = 0; i < 4; ++i) {
            float mv = fmaxf(sf[0][i], sf[1][i]);
            mv = fmaxf(mv, __shfl_xor(mv, 1));
            mv = fmaxf(mv, __shfl_xor(mv, 2));
            mv = fmaxf(mv, __shfl_xor(mv, 4));
            mv = fmaxf(mv, __shfl_xor(mv, 8));
            float mnew = fmaxf(m_run[i], mv);
            float sc = __expf(m_run[i] - mnew);
            l_run[i] *= sc;
            m_run[i] = mnew;
#pragma unroll
            for (int dt = 0; dt < 8; ++dt) acc[dt][i] *= sc;
        }
        // ---- exp, stage P into LDS in PV-A-fragment layout
#pragma unroll
        for (int pt = 0; pt < 2; ++pt) {
#pragma unroll
            for (int i = 0; i < 4; ++i) {
                float e = __expf(sf[pt][i] - m_run[i]);
                l_run[i] += e;
                plds[g4 * 4 + i][pt * 16 + r] = (__bf16)e;
            }
        }
        // ---- stage V to LDS (loads landed under QK+softmax); XOR bit-4 with row>>3&1
#pragma unroll
        for (int t = 0; t < 16; ++t) {
            int row = t * 2 + vrow2;
            int c2  = vcol ^ (((row >> 3) & 1) << 4);
            *(float4*)&vlds[row][c2] = vreg[t];
        }
        asm volatile("s_waitcnt lgkmcnt(0)" ::: "memory");
        __builtin_amdgcn_sched_barrier(0);
        bf16x8 pa = *(const bf16x8*)&plds[r][g4 * 8];
        // ---- PV from LDS (read applies same XOR; row>>3&1 == g4&1)
#pragma unroll
        for (int dt = 0; dt < 8; ++dt) {
            bf16x8 vf;
            int cread = (dt * 16 + r) ^ ((g4 & 1) << 4);
#pragma unroll
            for (int j = 0; j < 8; ++j) vf[j] = (__bf16)vlds[g4 * 8 + j][cread];
            acc[dt] = __builtin_amdgcn_mfma_f32_16x16x32_bf16(pa, vf, acc[dt], 0, 0, 0);
        }
        asm volatile("s_waitcnt lgkmcnt(0)" ::: "memory");
        __builtin_amdgcn_sched_barrier(0);
    }
    // ---- finalize l across the 16-lane group
#pragma unroll
    for (int i = 0; i < 4; ++i) {
        float lv = l_run[i];
        lv += __shfl_xor(lv, 1);
        lv += __shfl_xor(lv, 2);
        lv += __shfl_xor(lv, 4);
        lv += __shfl_xor(lv, 8);
        l_run[i] = lv;
    }
    float* pb = part + ((size_t)bg * NSPLIT_ + split) * 16 * 130;
#pragma unroll
    for (int dt = 0; dt < 8; ++dt)
#pragma unroll
        for (int i = 0; i < 4; ++i)
            pb[(g4 * 4 + i) * 130 + dt * 16 + r] = acc[dt][i];
    if (r == 0) {
#pragma unroll
        for (int i = 0; i < 4; ++i) {
            pb[(g4 * 4 + i) * 130 + 128] = m_run[i];
            pb[(g4 * 4 + i) * 130 + 129] = l_run[i];
        }
    }
}

// ---------------------------------------------------------------- attention combine (parallel)
// grid (B_*HKV_, 2), 1024 threads: block (bg,c) covers d in [c*64, c*64+64)
__global__ __launch_bounds__(1024) void attn_comb_k(const float* __restrict__ part,
                                                    const int* __restrict__ ctxl,
                                                    __bf16* __restrict__ ctxb)
{
    int bg = blockIdx.x;
    int c  = blockIdx.y;
    int b = bg >> 1, g = bg & 1;
    int ctx = ctxl[b];
    int ns = ctx / WAVE_POS_ + 1;
    const float* pb = part + (size_t)bg * NSPLIT_ * 16 * 130;
    __shared__ float mlm[NSPLIT_][16], wgt[NSPLIT_][16];
    __shared__ float Mh[16], Ih[16];
    int t = threadIdx.x;
    if (t < NSPLIT_ * 16) {
        int s = t >> 4, h = t & 15;
        mlm[s][h] = pb[(s * 16 + h) * 130 + 128];
        wgt[s][h] = pb[(s * 16 + h) * 130 + 129];
    }
    __syncthreads();
    if (t < 16) {
        int h = t;
        float M = -1e30f;
        for (int s = 0; s < ns; ++s) M = fmaxf(M, mlm[s][h]);
        float den = 0.f;
        for (int s = 0; s < ns; ++s) den += __expf(mlm[s][h] - M) * wgt[s][h];
        Mh[h] = M; Ih[h] = 1.f / den;
    }
    __syncthreads();
    if (t < NSPLIT_ * 16) {
        int s = t >> 4, h = t & 15;
        wgt[s][h] = __expf(mlm[s][h] - Mh[h]) * Ih[h];
    }
    __syncthreads();
    int h = t >> 6, dd = (t & 63) + c * 64;
    float o = 0.f;
    for (int s = 0; s < ns; ++s)
        o += wgt[s][h] * pb[(s * 16 + h) * 130 + dd];
    ctxb[(size_t)b * HID_ + (g * GQ_ + h) * D_ + dd] = (__bf16)o;
}

// ---------------------------------------------------------------- dense reduce (wide): grid (B_,4)
__global__ __launch_bounds__(1024) void dense_red_k(const float* __restrict__ hidden,
                                                    const float* __restrict__ partd, // [KS_DEN_][32][HID_]
                                                    float* __restrict__ xout,
                                                    float* __restrict__ ssq) // [B_][4]
{
    int b = blockIdx.x;
    int i = blockIdx.y * 1024 + threadIdx.x;
    float v = hidden[(size_t)b * HID_ + i];
#pragma unroll
    for (int p = 0; p < KS_DEN_; ++p) v += partd[((size_t)p * B_ + b) * HID_ + i];
    xout[(size_t)b * HID_ + i] = v;
    float ss = v * v;
#pragma unroll
    for (int m = 1; m < 64; m <<= 1) ss += __shfl_xor(ss, m);
    __shared__ float wred[16];
    if ((threadIdx.x & 63) == 0) wred[threadIdx.x >> 6] = ss;
    __syncthreads();
    if (threadIdx.x == 0) {
        float s = 0.f;
#pragma unroll
        for (int wv = 0; wv < 16; ++wv) s += wred[wv];
        ssq[b * 4 + blockIdx.y] = s;
    }
}

// ---------------------------------------------------------------- rmsnorm2 (narrow): grid B_
__global__ __launch_bounds__(1024) void rms2_k(const float* __restrict__ xbuf,
                                               const float* __restrict__ ssq,
                                               const float* __restrict__ wln2,
                                               __bf16* __restrict__ a2)
{
    int b = blockIdx.x;
    float ss = ssq[b * 4] + ssq[b * 4 + 1] + ssq[b * 4 + 2] + ssq[b * 4 + 3];
    float rs = rsqrtf(ss / HID_ + EPS_);
#pragma unroll
    for (int it = 0; it < 4; ++it) {
        int i = threadIdx.x + it * 1024;
        a2[(size_t)b * HID_ + i] = (__bf16)(wln2[i] * xbuf[(size_t)b * HID_ + i] * rs);
    }
}

// ---------------------------------------------------------------- swiglu activation (sums KS_H4H_ slabs)
__global__ __launch_bounds__(256) void act_k(const float* __restrict__ gu, // [KS_H4H_][32][2*FFN_]
                                             __bf16* __restrict__ act)
{
    int i = blockIdx.x * 256 + threadIdx.x;
    int b = blockIdx.y;
    if (i < FFN_) {
        float gv = 0.f, uv = 0.f;
#pragma unroll
        for (int p = 0; p < KS_H4H_; ++p) {
            const float* gp = gu + ((size_t)p * B_ + b) * 2 * FFN_;
            gv += gp[i];
            uv += gp[FFN_ + i];
        }
        float s = gv / (1.f + __expf(-gv));
        act[(size_t)b * FFN_ + i] = (__bf16)(s * uv);
    }
}

// ---------------------------------------------------------------- final residual
__global__ __launch_bounds__(256) void out_epi_k(const float* __restrict__ x,
                                                 const float* __restrict__ part4, // [KS_4HH_][32][HID_]
                                                 float* __restrict__ out)
{
    int i = blockIdx.x * 256 + threadIdx.x;
    float v = x[i];
#pragma unroll
    for (int p = 0; p < KS_4HH_; ++p) v += part4[(size_t)p * (B_ * HID_) + i];
    out[i] = v;
}

// ---------------------------------------------------------------- launch
extern "C" void kernel_launch(void* const* d_in, const int* in_sizes, int n_in,
                              void* d_out, int out_size, void* d_ws, size_t ws_size,
                              hipStream_t stream)
{
    const float* hidden  = (const float*)d_in[0];
    const int*   ctxl    = (const int*)d_in[1];
    const float* kcache  = (const float*)d_in[2];
    const float* vcache  = (const float*)d_in[3];
    const float* w_ln1   = (const float*)d_in[4];
    const float* w_ln2   = (const float*)d_in[5];
    const float* w_qkv   = (const float*)d_in[6];
    const float* b_qkv   = (const float*)d_in[7];
    const float* w_dense = (const float*)d_in[8];
    const float* w_h4h   = (const float*)d_in[9];
    const float* w_4hh   = (const float*)d_in[10];
    float* out = (float*)d_out;

    char* ws = (char*)d_ws;
    size_t off = 0;
    auto alloc = [&](size_t bytes) -> void* {
        void* p = ws + off;
        off += (bytes + 255) & ~(size_t)255;
        return p;
    };
    __bf16* a0    = (__bf16*)alloc((size_t)B_ * HID_ * 2);
    float*  partq = (float*) alloc((size_t)KS_QKV_ * B_ * NQKV_ * 4);
    __bf16* qbf   = (__bf16*)alloc((size_t)B_ * HID_ * 2);
    float*  knew  = (float*) alloc((size_t)B_ * HKV_ * D_ * 4);
    float*  vnew  = (float*) alloc((size_t)B_ * HKV_ * D_ * 4);
    float*  apart = (float*) alloc((size_t)B_ * HKV_ * NSPLIT_ * 16 * 130 * 4);
    __bf16* ctxb  = (__bf16*)alloc((size_t)B_ * HID_ * 2);
    float*  partd = (float*) alloc((size_t)KS_DEN_ * B_ * HID_ * 4);
    float*  xbuf  = (float*) alloc((size_t)B_ * HID_ * 4);
    float*  ssq   = (float*) alloc((size_t)B_ * 4 * 4);
    __bf16* a2    = (__bf16*)alloc((size_t)B_ * HID_ * 2);
    float*  gu    = (float*) alloc((size_t)KS_H4H_ * B_ * 2 * FFN_ * 4);
    __bf16* actb  = (__bf16*)alloc((size_t)B_ * FFN_ * 2);
    float*  part4 = (float*) alloc((size_t)KS_4HH_ * B_ * HID_ * 4);
    (void)ws_size; (void)in_sizes; (void)n_in; (void)out_size;

    hipLaunchKernelGGL(rmsnorm1_k, dim3(B_), dim3(1024), 0, stream, hidden, w_ln1, a0);
    hipLaunchKernelGGL((gemm16<HID_, NQKV_, KS_QKV_>), dim3(NQKV_ / 128, KS_QKV_), dim3(256), 0, stream, a0, w_qkv, partq);
    hipLaunchKernelGGL(qkv_epi_k, dim3(B_, 4), dim3(1024), 0, stream, partq, b_qkv, ctxl, qbf, knew, vnew);
    hipLaunchKernelGGL(attn_k, dim3(B_ * HKV_, NSPLIT_ / 4), dim3(256), 0, stream,
                       kcache, vcache, knew, vnew, qbf, ctxl, apart);
    hipLaunchKernelGGL(attn_comb_k, dim3(B_ * HKV_, 2), dim3(1024), 0, stream, apart, ctxl, ctxb);
    hipLaunchKernelGGL((gemm16<HID_, HID_, KS_DEN_>), dim3(HID_ / 128, KS_DEN_), dim3(256), 0, stream, ctxb, w_dense, partd);
    hipLaunchKernelGGL(dense_red_k, dim3(B_, 4), dim3(1024), 0, stream, hidden, partd, xbuf, ssq);
    hipLaunchKernelGGL(rms2_k, dim3(B_), dim3(1024), 0, stream, xbuf, ssq, w_ln2, a2);
    hipLaunchKernelGGL((gemm16<HID_, 2 * FFN_, KS_H4H_>), dim3(2 * FFN_ / 128, KS_H4H_), dim3(256), 0, stream, a2, w_h4h, gu);
    hipLaunchKernelGGL(act_k, dim3((FFN_ + 255) / 256, B_), dim3(256), 0, stream, gu, actb);
    hipLaunchKernelGGL((gemm16<FFN_, HID_, KS_4HH_>), dim3(HID_ / 128, KS_4HH_), dim3(256), 0, stream, actb, w_4hh, part4);
    hipLaunchKernelGGL(out_epi_k, dim3(B_ * HID_ / 256), dim3(256), 0, stream, xbuf, part4, out);
}

// Round 11
// 261.589 us; speedup vs baseline: 1.0478x; 1.0144x over previous
//
#include <hip/hip_runtime.h>
#include <hip/hip_bf16.h>

#define B_    32
#define L_    4096
#define H_    32
#define HKV_  2
#define GQ_   16
#define D_    128
#define HID_  4096
#define FFN_  13696
#define NQKV_ 4608
#define ROT_  64
#define EPS_  1e-5f

#define WAVE_POS_ 128
#define NSPLIT_   32   // L_ / WAVE_POS_

// KSPLIT per GEMM — grids <= 768 (3 blocks/CU co-residency cap at 48KB LDS).
// With atomic accumulation these no longer multiply memory traffic.
#define KS_QKV_  16    // 36*16 = 576 blocks
#define KS_DEN_  24    // 32*24 = 768 blocks
#define KS_H4H_  3     // 214*3 = 642 blocks
#define KS_4HH_  24    // 32*24 = 768 blocks

typedef __attribute__((ext_vector_type(8))) __bf16 bf16x8;
typedef __attribute__((ext_vector_type(4))) float  f32x4;

__device__ __forceinline__ void gl_lds16(const float* g, float* l) {
    __builtin_amdgcn_global_load_lds((const __attribute__((address_space(1))) void*)g,
                                     (__attribute__((address_space(3))) void*)l, 16, 0, 0);
}

// ---------------------------------------------------------------- rmsnorm1 (+ qacc=bias init)
__global__ __launch_bounds__(1024) void rmsnorm1_k(const float* __restrict__ x,
                                                   const float* __restrict__ w,
                                                   const float* __restrict__ bias,
                                                   __bf16* __restrict__ out,
                                                   float* __restrict__ qacc)
{
    int b = blockIdx.x;
    // init qkv accumulator with bias (gemm_qkv atomically adds onto this)
    for (int i = threadIdx.x; i < NQKV_; i += 1024)
        qacc[(size_t)b * NQKV_ + i] = bias[i];
    const float* row = x + (size_t)b * HID_;
    float vals[4];
    float ss = 0.f;
#pragma unroll
    for (int i = 0; i < 4; ++i) {
        vals[i] = row[threadIdx.x + i * 1024];
        ss += vals[i] * vals[i];
    }
#pragma unroll
    for (int m = 1; m < 64; m <<= 1) ss += __shfl_xor(ss, m);
    __shared__ float wred[16];
    if ((threadIdx.x & 63) == 0) wred[threadIdx.x >> 6] = ss;
    __syncthreads();
    ss = 0.f;
#pragma unroll
    for (int wv = 0; wv < 16; ++wv) ss += wred[wv];
    float rs = rsqrtf(ss / HID_ + EPS_);
#pragma unroll
    for (int i = 0; i < 4; ++i) {
        int idx = threadIdx.x + i * 1024;
        out[(size_t)b * HID_ + idx] = (__bf16)(w[idx] * vals[i] * rs);
    }
}

// ---------------------------------------------------------------- skinny GEMM, atomic epilogue
// A: [32][K] bf16 row-major.  W: [K][N] f32.  C: [32][N] f32 (pre-initialized;
// this kernel ATOMICALLY accumulates its k-slab contribution).
template<int K, int N, int KSPLIT>
__global__ __launch_bounds__(256) void gemm16(const __bf16* __restrict__ A,
                                              const float* __restrict__ W,
                                              float* __restrict__ C)
{
    static_assert(K % 32 == 0, "K");
    constexpr int ksteps = K / 32;
    const int lane = threadIdx.x & 63;
    const int wid  = threadIdx.x >> 6;
    const int n0   = blockIdx.x * 128;
    const int cw   = wid * 32;
    const int r    = lane & 15;
    const int g4   = lane >> 4;
    const int s0   = (ksteps * (int)blockIdx.y) / KSPLIT;
    const int s1   = (ksteps * (int)(blockIdx.y + 1)) / KSPLIT;

    __shared__ float tiles[3][32][128];   // 48 KB

    const int rhalf = lane >> 5;          // 0/1 row within instruction
    const int mslot = lane & 31;          // 16B slot within row
    auto stage = [&](int s, float* dst) {
        if (s >= s1) return;
#pragma unroll
        for (int it = 0; it < 4; ++it) {
            int row  = wid * 8 + it * 2 + rhalf;
            int gcol = ((((mslot >> 1) ^ (row >> 3)) << 3) | ((mslot & 1) << 2));
            const float* src = W + (size_t)(s * 32 + row) * N + n0 + gcol;
            gl_lds16(src, dst + (size_t)(wid * 8 + it * 2) * 128);
        }
    };

    f32x4 acc00 = {0.f,0.f,0.f,0.f}, acc01 = acc00, acc10 = acc00, acc11 = acc00;
    const __bf16* a0p = A + (size_t)r * K;
    const __bf16* a1p = A + (size_t)(r + 16) * K;

    stage(s0,     &tiles[0][0][0]);
    stage(s0 + 1, &tiles[1][0][0]);

    const int c0 = cw + r, c1 = cw + r + 16;
    const int i0 = (((c0 >> 3) ^ g4) << 3) | (c0 & 7);
    const int i1 = (((c1 >> 3) ^ g4) << 3) | (c1 & 7);

    int bufc = 0;
    for (int s = s0; s < s1; ++s) {
        if (s + 1 < s1) asm volatile("s_waitcnt vmcnt(4)" ::: "memory");
        else            asm volatile("s_waitcnt vmcnt(0)" ::: "memory");
        __builtin_amdgcn_s_barrier();
        __builtin_amdgcn_sched_barrier(0);
        int bs = bufc + 2; if (bs >= 3) bs -= 3;
        stage(s + 2, &tiles[bs][0][0]);

        bf16x8 av0 = *(const bf16x8*)(a0p + s * 32 + g4 * 8);
        bf16x8 av1 = *(const bf16x8*)(a1p + s * 32 + g4 * 8);
        const float (*tile)[128] = tiles[bufc];
        bf16x8 b0f, b1f;
#pragma unroll
        for (int j = 0; j < 8; ++j) {
            b0f[j] = (__bf16)tile[g4 * 8 + j][i0];
            b1f[j] = (__bf16)tile[g4 * 8 + j][i1];
        }
        acc00 = __builtin_amdgcn_mfma_f32_16x16x32_bf16(av0, b0f, acc00, 0, 0, 0);
        acc10 = __builtin_amdgcn_mfma_f32_16x16x32_bf16(av1, b0f, acc10, 0, 0, 0);
        acc01 = __builtin_amdgcn_mfma_f32_16x16x32_bf16(av0, b1f, acc01, 0, 0, 0);
        acc11 = __builtin_amdgcn_mfma_f32_16x16x32_bf16(av1, b1f, acc11, 0, 0, 0);
        bufc = (bufc + 1 < 3) ? bufc + 1 : 0;
    }

    float* cp = C + n0 + cw;
#pragma unroll
    for (int i = 0; i < 4; ++i) {
        unsafeAtomicAdd(&cp[(size_t)(g4 * 4 + i) * N + r],           acc00[i]);
        unsafeAtomicAdd(&cp[(size_t)(g4 * 4 + i) * N + r + 16],      acc01[i]);
        unsafeAtomicAdd(&cp[(size_t)(16 + g4 * 4 + i) * N + r],      acc10[i]);
        unsafeAtomicAdd(&cp[(size_t)(16 + g4 * 4 + i) * N + r + 16], acc11[i]);
    }
}

// ---------------------------------------------------------------- qkv epilogue, wide: grid (B_,4)
// reads finished qacc (bias included), applies rope / split.
__global__ __launch_bounds__(1024) void qkv_epi_k(const float* __restrict__ qacc, // [32][NQKV_]
                                                  const int* __restrict__ ctxl,
                                                  __bf16* __restrict__ qbf,
                                                  float* __restrict__ knew,
                                                  float* __restrict__ vnew)
{
    __shared__ float rowv[1152];
    __shared__ float cs[32], sn[32];
    int b = blockIdx.x, base = blockIdx.y * 1152;
    int pos = ctxl[b];
    if (threadIdx.x < 32) {
        int t = threadIdx.x;
        float inv = powf(10000.f, -(float)t * (1.0f / 32.0f));
        float f = (float)pos * inv;
        float sv, cv; sincosf(f, &sv, &cv);
        cs[t] = cv; sn[t] = sv;
    }
    for (int i0 = threadIdx.x; i0 < 1152; i0 += 1024)
        rowv[i0] = qacc[(size_t)b * NQKV_ + base + i0];
    __syncthreads();
    const float qscale = 0.08838834764831845f; // 1/sqrt(128)
    for (int i0 = threadIdx.x; i0 < 1152; i0 += 1024) {
        int i = base + i0;
        int d = i & 127;
        if (i < HID_) {
            float o;
            if (d < ROT_) {
                int t = d >> 1;
                float cv = cs[t], sv = sn[t];
                float x1 = rowv[(i & ~1) - base], x2 = rowv[(i | 1) - base];
                o = (d & 1) ? (x2 * cv + x1 * sv) : (x1 * cv - x2 * sv);
            } else o = rowv[i0];
            qbf[(size_t)b * HID_ + i] = (__bf16)(o * qscale);
        } else {
            int j = i - HID_;            // 0..511
            if (j < HKV_ * D_) {         // k region
                float o;
                if (d < ROT_) {
                    int t = d >> 1;
                    float cv = cs[t], sv = sn[t];
                    float x1 = rowv[(i & ~1) - base], x2 = rowv[(i | 1) - base];
                    o = (d & 1) ? (x2 * cv + x1 * sv) : (x1 * cv - x2 * sv);
                } else o = rowv[i0];
                knew[(size_t)b * HKV_ * D_ + j] = o;
            } else {                     // v region
                vnew[(size_t)b * HKV_ * D_ + (j - HKV_ * D_)] = rowv[i0];
            }
        }
    }
}

// ---------------------------------------------------------------- flash-decode attention (R7-exact)
// part: [B*HKV][NSPLIT_][16][130]  (128 acc, m, l) per head
__global__ __launch_bounds__(256) void attn_k(const float* __restrict__ kc,
                                              const float* __restrict__ vc,
                                              const float* __restrict__ knew,
                                              const float* __restrict__ vnew,
                                              const __bf16* __restrict__ qbf,
                                              const int* __restrict__ ctxl,
                                              float* __restrict__ part)
{
    const int bg  = blockIdx.x;            // 0..63
    const int b   = bg >> 1, g = bg & 1;
    const int wid = threadIdx.x >> 6;
    const int split = blockIdx.y * 4 + wid;  // 0..NSPLIT_-1
    const int ctx = ctxl[b];
    const int p0  = split * WAVE_POS_;
    __shared__ __bf16 plds_all[4][16][40];
    if (p0 > ctx) return;
    const int pend = min(p0 + WAVE_POS_ - 1, ctx);
    const int lane = threadIdx.x & 63;
    const int r = lane & 15, g4 = lane >> 4;

    bf16x8 qf[4];
    {
        const __bf16* qp = qbf + (size_t)b * HID_ + (g * GQ_ + r) * D_ + g4 * 8;
#pragma unroll
        for (int kk = 0; kk < 4; ++kk) qf[kk] = *(const bf16x8*)(qp + kk * 32);
    }
    f32x4 acc[8];
#pragma unroll
    for (int dt = 0; dt < 8; ++dt) acc[dt] = (f32x4){0.f,0.f,0.f,0.f};
    float m_run[4], l_run[4];
#pragma unroll
    for (int i = 0; i < 4; ++i) { m_run[i] = -1e30f; l_run[i] = 0.f; }

    auto plds = plds_all[wid];
    const float* kbase = kc + ((size_t)b * L_ * HKV_ + g) * D_;
    const float* vbase = vc + ((size_t)b * L_ * HKV_ + g) * D_;
    const float* knp = knew + (size_t)(b * HKV_ + g) * D_;
    const float* vnp = vnew + (size_t)(b * HKV_ + g) * D_;

    for (int pc = p0; pc <= pend; pc += 32) {
        f32x4 sf[2];
#pragma unroll
        for (int pt = 0; pt < 2; ++pt) {
            int pos = pc + pt * 16 + r;
            const float* krow = (pos == ctx) ? knp : kbase + (size_t)pos * (HKV_ * D_);
            f32x4 s = {0.f,0.f,0.f,0.f};
#pragma unroll
            for (int kk = 0; kk < 4; ++kk) {
                const float4* kp = (const float4*)(krow + kk * 32 + g4 * 8);
                float4 fa = kp[0], fb = kp[1];
                bf16x8 kf = { (__bf16)fa.x, (__bf16)fa.y, (__bf16)fa.z, (__bf16)fa.w,
                              (__bf16)fb.x, (__bf16)fb.y, (__bf16)fb.z, (__bf16)fb.w };
                s = __builtin_amdgcn_mfma_f32_16x16x32_bf16(qf[kk], kf, s, 0, 0, 0);
            }
            sf[pt] = s;
        }
#pragma unroll
        for (int pt = 0; pt < 2; ++pt) {
            int pos = pc + pt * 16 + r;
            if (pos > ctx) {
#pragma unroll
                for (int i = 0; i < 4; ++i) sf[pt][i] = -1e30f;
            }
        }
#pragma unroll
        for (int i = 0; i < 4; ++i) {
            float mv = fmaxf(sf[0][i], sf[1][i]);
            mv = fmaxf(mv, __shfl_xor(mv, 1));
            mv = fmaxf(mv, __shfl_xor(mv, 2));
            mv = fmaxf(mv, __shfl_xor(mv, 4));
            mv = fmaxf(mv, __shfl_xor(mv, 8));
            float mnew = fmaxf(m_run[i], mv);
            float sc = __expf(m_run[i] - mnew);
            l_run[i] *= sc;
            m_run[i] = mnew;
#pragma unroll
            for (int dt = 0; dt < 8; ++dt) acc[dt][i] *= sc;
        }
#pragma unroll
        for (int pt = 0; pt < 2; ++pt) {
#pragma unroll
            for (int i = 0; i < 4; ++i) {
                float e = __expf(sf[pt][i] - m_run[i]);
                l_run[i] += e;
                plds[g4 * 4 + i][pt * 16 + r] = (__bf16)e;
            }
        }
        asm volatile("s_waitcnt lgkmcnt(0)" ::: "memory");
        __builtin_amdgcn_sched_barrier(0);
        bf16x8 pa = *(const bf16x8*)&plds[r][g4 * 8];
        const float* vrows[8];
#pragma unroll
        for (int j = 0; j < 8; ++j) {
            int pos = pc + g4 * 8 + j;
            vrows[j] = (pos == ctx) ? vnp : vbase + (size_t)pos * (HKV_ * D_);
        }
#pragma unroll
        for (int dt = 0; dt < 8; ++dt) {
            bf16x8 vf;
#pragma unroll
            for (int j = 0; j < 8; ++j) vf[j] = (__bf16)vrows[j][dt * 16 + r];
            acc[dt] = __builtin_amdgcn_mfma_f32_16x16x32_bf16(pa, vf, acc[dt], 0, 0, 0);
        }
        asm volatile("s_waitcnt lgkmcnt(0)" ::: "memory");
        __builtin_amdgcn_sched_barrier(0);
    }
#pragma unroll
    for (int i = 0; i < 4; ++i) {
        float lv = l_run[i];
        lv += __shfl_xor(lv, 1);
        lv += __shfl_xor(lv, 2);
        lv += __shfl_xor(lv, 4);
        lv += __shfl_xor(lv, 8);
        l_run[i] = lv;
    }
    float* pb = part + ((size_t)bg * NSPLIT_ + split) * 16 * 130;
#pragma unroll
    for (int dt = 0; dt < 8; ++dt)
#pragma unroll
        for (int i = 0; i < 4; ++i)
            pb[(g4 * 4 + i) * 130 + dt * 16 + r] = acc[dt][i];
    if (r == 0) {
#pragma unroll
        for (int i = 0; i < 4; ++i) {
            pb[(g4 * 4 + i) * 130 + 128] = m_run[i];
            pb[(g4 * 4 + i) * 130 + 129] = l_run[i];
        }
    }
}

// ---------------------------------------------------------------- attention combine (+ dacc=hidden init)
// grid (B_*HKV_, 2), 1024 threads: block (bg,c) covers d in [c*64, c*64+64)
__global__ __launch_bounds__(1024) void attn_comb_k(const float* __restrict__ part,
                                                    const int* __restrict__ ctxl,
                                                    const float* __restrict__ hidden,
                                                    __bf16* __restrict__ ctxb,
                                                    float* __restrict__ dacc)
{
    int bg = blockIdx.x;
    int c  = blockIdx.y;
    int b = bg >> 1, g = bg & 1;
    // init dense accumulator with residual input: segment (g*2+c)*1024
    {
        int seg = (g * 2 + c) * 1024 + threadIdx.x;
        dacc[(size_t)b * HID_ + seg] = hidden[(size_t)b * HID_ + seg];
    }
    int ctx = ctxl[b];
    int ns = ctx / WAVE_POS_ + 1;
    const float* pb = part + (size_t)bg * NSPLIT_ * 16 * 130;
    __shared__ float mlm[NSPLIT_][16], wgt[NSPLIT_][16];
    __shared__ float Mh[16], Ih[16];
    int t = threadIdx.x;
    if (t < NSPLIT_ * 16) {
        int s = t >> 4, h = t & 15;
        mlm[s][h] = pb[(s * 16 + h) * 130 + 128];
        wgt[s][h] = pb[(s * 16 + h) * 130 + 129];
    }
    __syncthreads();
    if (t < 16) {
        int h = t;
        float M = -1e30f;
        for (int s = 0; s < ns; ++s) M = fmaxf(M, mlm[s][h]);
        float den = 0.f;
        for (int s = 0; s < ns; ++s) den += __expf(mlm[s][h] - M) * wgt[s][h];
        Mh[h] = M; Ih[h] = 1.f / den;
    }
    __syncthreads();
    if (t < NSPLIT_ * 16) {
        int s = t >> 4, h = t & 15;
        wgt[s][h] = __expf(mlm[s][h] - Mh[h]) * Ih[h];
    }
    __syncthreads();
    int h = t >> 6, dd = (t & 63) + c * 64;
    float o = 0.f;
    for (int s = 0; s < ns; ++s)
        o += wgt[s][h] * pb[(s * 16 + h) * 130 + dd];
    ctxb[(size_t)b * HID_ + (g * GQ_ + h) * D_ + dd] = (__bf16)o;
}

// ---------------------------------------------------------------- dense reduce (wide): grid (B_,4)
// dacc already = hidden + dense_out (atomics). Writes xbuf, out (=x, init for 4hh), ssq.
__global__ __launch_bounds__(1024) void dense_red_k(const float* __restrict__ dacc,
                                                    float* __restrict__ xout,
                                                    float* __restrict__ outbuf,
                                                    float* __restrict__ ssq) // [B_][4]
{
    int b = blockIdx.x;
    int i = blockIdx.y * 1024 + threadIdx.x;
    float v = dacc[(size_t)b * HID_ + i];
    xout[(size_t)b * HID_ + i] = v;
    outbuf[(size_t)b * HID_ + i] = v;
    float ss = v * v;
#pragma unroll
    for (int m = 1; m < 64; m <<= 1) ss += __shfl_xor(ss, m);
    __shared__ float wred[16];
    if ((threadIdx.x & 63) == 0) wred[threadIdx.x >> 6] = ss;
    __syncthreads();
    if (threadIdx.x == 0) {
        float s = 0.f;
#pragma unroll
        for (int wv = 0; wv < 16; ++wv) s += wred[wv];
        ssq[b * 4 + blockIdx.y] = s;
    }
}

// ---------------------------------------------------------------- rmsnorm2 (+ guacc=0 init): grid B_
__global__ __launch_bounds__(1024) void rms2_k(const float* __restrict__ xbuf,
                                               const float* __restrict__ ssq,
                                               const float* __restrict__ wln2,
                                               __bf16* __restrict__ a2,
                                               float* __restrict__ guacc)
{
    int b = blockIdx.x;
    for (int i = threadIdx.x; i < 2 * FFN_; i += 1024)
        guacc[(size_t)b * 2 * FFN_ + i] = 0.f;
    float ss = ssq[b * 4] + ssq[b * 4 + 1] + ssq[b * 4 + 2] + ssq[b * 4 + 3];
    float rs = rsqrtf(ss / HID_ + EPS_);
#pragma unroll
    for (int it = 0; it < 4; ++it) {
        int i = threadIdx.x + it * 1024;
        a2[(size_t)b * HID_ + i] = (__bf16)(wln2[i] * xbuf[(size_t)b * HID_ + i] * rs);
    }
}

// ---------------------------------------------------------------- swiglu activation (single slab)
__global__ __launch_bounds__(256) void act_k(const float* __restrict__ guacc, // [32][2*FFN_]
                                             __bf16* __restrict__ act)
{
    int i = blockIdx.x * 256 + threadIdx.x;
    int b = blockIdx.y;
    if (i < FFN_) {
        const float* gp = guacc + (size_t)b * 2 * FFN_;
        float gv = gp[i];
        float uv = gp[FFN_ + i];
        float s = gv / (1.f + __expf(-gv));
        act[(size_t)b * FFN_ + i] = (__bf16)(s * uv);
    }
}

// ---------------------------------------------------------------- launch
extern "C" void kernel_launch(void* const* d_in, const int* in_sizes, int n_in,
                              void* d_out, int out_size, void* d_ws, size_t ws_size,
                              hipStream_t stream)
{
    const float* hidden  = (const float*)d_in[0];
    const int*   ctxl    = (const int*)d_in[1];
    const float* kcache  = (const float*)d_in[2];
    const float* vcache  = (const float*)d_in[3];
    const float* w_ln1   = (const float*)d_in[4];
    const float* w_ln2   = (const float*)d_in[5];
    const float* w_qkv   = (const float*)d_in[6];
    const float* b_qkv   = (const float*)d_in[7];
    const float* w_dense = (const float*)d_in[8];
    const float* w_h4h   = (const float*)d_in[9];
    const float* w_4hh   = (const float*)d_in[10];
    float* out = (float*)d_out;

    char* ws = (char*)d_ws;
    size_t off = 0;
    auto alloc = [&](size_t bytes) -> void* {
        void* p = ws + off;
        off += (bytes + 255) & ~(size_t)255;
        return p;
    };
    __bf16* a0    = (__bf16*)alloc((size_t)B_ * HID_ * 2);
    float*  qacc  = (float*) alloc((size_t)B_ * NQKV_ * 4);
    __bf16* qbf   = (__bf16*)alloc((size_t)B_ * HID_ * 2);
    float*  knew  = (float*) alloc((size_t)B_ * HKV_ * D_ * 4);
    float*  vnew  = (float*) alloc((size_t)B_ * HKV_ * D_ * 4);
    float*  apart = (float*) alloc((size_t)B_ * HKV_ * NSPLIT_ * 16 * 130 * 4);
    __bf16* ctxb  = (__bf16*)alloc((size_t)B_ * HID_ * 2);
    float*  dacc  = (float*) alloc((size_t)B_ * HID_ * 4);
    float*  xbuf  = (float*) alloc((size_t)B_ * HID_ * 4);
    float*  ssq   = (float*) alloc((size_t)B_ * 4 * 4);
    __bf16* a2    = (__bf16*)alloc((size_t)B_ * HID_ * 2);
    float*  guacc = (float*) alloc((size_t)B_ * 2 * FFN_ * 4);
    __bf16* actb  = (__bf16*)alloc((size_t)B_ * FFN_ * 2);
    (void)ws_size; (void)in_sizes; (void)n_in; (void)out_size;

    hipLaunchKernelGGL(rmsnorm1_k, dim3(B_), dim3(1024), 0, stream, hidden, w_ln1, b_qkv, a0, qacc);
    hipLaunchKernelGGL((gemm16<HID_, NQKV_, KS_QKV_>), dim3(NQKV_ / 128, KS_QKV_), dim3(256), 0, stream, a0, w_qkv, qacc);
    hipLaunchKernelGGL(qkv_epi_k, dim3(B_, 4), dim3(1024), 0, stream, qacc, ctxl, qbf, knew, vnew);
    hipLaunchKernelGGL(attn_k, dim3(B_ * HKV_, NSPLIT_ / 4), dim3(256), 0, stream,
                       kcache, vcache, knew, vnew, qbf, ctxl, apart);
    hipLaunchKernelGGL(attn_comb_k, dim3(B_ * HKV_, 2), dim3(1024), 0, stream, apart, ctxl, hidden, ctxb, dacc);
    hipLaunchKernelGGL((gemm16<HID_, HID_, KS_DEN_>), dim3(HID_ / 128, KS_DEN_), dim3(256), 0, stream, ctxb, w_dense, dacc);
    hipLaunchKernelGGL(dense_red_k, dim3(B_, 4), dim3(1024), 0, stream, dacc, xbuf, out, ssq);
    hipLaunchKernelGGL(rms2_k, dim3(B_), dim3(1024), 0, stream, xbuf, ssq, w_ln2, a2, guacc);
    hipLaunchKernelGGL((gemm16<HID_, 2 * FFN_, KS_H4H_>), dim3(2 * FFN_ / 128, KS_H4H_), dim3(256), 0, stream, a2, w_h4h, guacc);
    hipLaunchKernelGGL(act_k, dim3((FFN_ + 255) / 256, B_), dim3(256), 0, stream, guacc, actb);
    hipLaunchKernelGGL((gemm16<FFN_, HID_, KS_4HH_>), dim3(HID_ / 128, KS_4HH_), dim3(256), 0, stream, actb, w_4hh, out);
}